// Round 17
// baseline (181.458 us; speedup 1.0000x reference)
//
#include <hip/hip_runtime.h>

typedef short bf16x8 __attribute__((ext_vector_type(8)));
typedef float f32x4 __attribute__((ext_vector_type(4)));

#define DI __device__ __forceinline__

#define LOG2E 1.44269504088896f
#define QSCALE (0.17677669529663687f * 1.44269504088896f)

static DI unsigned short f2bf(float f) {
  union { float f; unsigned u; } v; v.f = f;
  unsigned r = v.u + 0x7FFFu + ((v.u >> 16) & 1u);  // RNE
  return (unsigned short)(r >> 16);
}

static DI unsigned cvt_pk_bf16(float lo, float hi) {
  unsigned r;
  asm("v_cvt_pk_bf16_f32 %0, %1, %2" : "=v"(r) : "v"(lo), "v"(hi));
  return r;
}

static DI float bflo(unsigned u) { return __uint_as_float(u << 16); }
static DI float bfhi(unsigned u) { return __uint_as_float(u & 0xffff0000u); }

// Async global->LDS, 16B per lane. LDS dest is wave-uniform base + lane*16.
static DI void gld16(const void* g, void* l) {
  __builtin_amdgcn_global_load_lds((__attribute__((address_space(1))) void*)g,
                                   (__attribute__((address_space(3))) void*)l,
                                   16, 0, 0);
}

// ---------------------------------------------------------------------------
// PREP kernel: cast_weights (blocks 0..1279) + rmsnorm_m (blocks 1280..9471).
// Resource-symmetric fusion (both <=32 VGPR, no LDS, memory-bound).
// Wt_qkvg: [N=1024][K=256] bf16 n-major. Wt_o: rows k-PERMUTED with
// pi(h*32+d) = h*32 + (d&15)*2 + (d>>4) (k-perm on both operands = no-op).
// ---------------------------------------------------------------------------
__global__ __launch_bounds__(256) void k_prep(
    const float* __restrict__ Wq, const float* __restrict__ Wk,
    const float* __restrict__ Wv, const float* __restrict__ Wg,
    const float* __restrict__ Wo,
    unsigned short* __restrict__ Wt_qkvg, unsigned short* __restrict__ Wt_o,
    const float* __restrict__ m, const float* __restrict__ w_norm_m,
    unsigned short* __restrict__ m_norm) {
  int bx = blockIdx.x;
  if (bx < 1280) {
    int t = bx * 256 + threadIdx.x;
    if (t < 262144) {
      int n = t & 1023, kk = t >> 10;
      const float* W = (n < 256) ? Wq : (n < 512) ? Wk : (n < 768) ? Wv : Wg;
      Wt_qkvg[(size_t)n * 256 + kk] = f2bf(W[kk * 256 + (n & 255)]);
    } else if (t < 262144 + 65536) {
      int u = t - 262144;
      int n = u & 255, kk = u >> 8;
      int h = kk >> 5, e = kk & 31;
      int d = (e >> 1) + ((e & 1) << 4);  // pi^-1
      Wt_o[n * 256 + kk] = f2bf(Wo[(h * 32 + d) * 256 + n]);
    }
    return;
  }
  // rmsnorm: one wave per 256-elem row, float4 per lane
  int wave = threadIdx.x >> 6, lane = threadIdx.x & 63;
  int row = (bx - 1280) * 4 + wave;
  const float4 x = *(const float4*)(m + (size_t)row * 256 + lane * 4);
  float ss = x.x * x.x + x.y * x.y + x.z * x.z + x.w * x.w;
#pragma unroll
  for (int mk = 1; mk < 64; mk <<= 1) ss += __shfl_xor(ss, mk, 64);
  float rms = rsqrtf(ss * (1.0f / 256.0f) + 1e-5f);
  const float4 wv = *(const float4*)(w_norm_m + lane * 4);
  ushort4 o;
  o.x = f2bf(x.x * rms * wv.x);
  o.y = f2bf(x.y * rms * wv.y);
  o.z = f2bf(x.z * rms * wv.z);
  o.w = f2bf(x.w * rms * wv.w);
  *(ushort4*)(m_norm + (size_t)row * 256 + lane * 4) = o;
}

// ---------------------------------------------------------------------------
// Pair bias -> bf16 packed SWAPPED-C-fragment layout, pre-scaled by log2(e).
// Attn computes D[k][q] = mfma(K,Q): lane l needs bias(i=q=l&15 of its tile,
// k = t*16 + 4*(l>>4) + r). Pack pairs along k (j0 even, j0+1):
//   u32 biasf[h][i16][t][l][w], l = (i&15) + 16*((j0&15)>>2), w = (j0>>1)&1
// Wave: half 0 -> j0 (even), half 1 -> j0+1, same i; pack via shfl_xor(32).
// z loads coalesced (2 adjacent rows = 1KB per wave).
// ---------------------------------------------------------------------------
__global__ __launch_bounds__(256) void k_pair_bias(
    const float* __restrict__ z, const float* __restrict__ z_mask,
    const float* __restrict__ w_norm_z, const float* __restrict__ Wz,
    unsigned* __restrict__ biasf) {
  int gw = blockIdx.x * 4 + (threadIdx.x >> 6);   // global wave 0..16383
  int lane = threadIdx.x & 63;
  int half = lane >> 5, li = lane & 31;
  f32x4 wzl[4], wzh[4];
#pragma unroll
  for (int i = 0; i < 4; ++i) {
    wzl[i] = *(const f32x4*)(Wz + (li * 4 + i) * 8);
    wzh[i] = *(const f32x4*)(Wz + (li * 4 + i) * 8 + 4);
  }
  const float4 wn = *(const float4*)(w_norm_z + li * 4);

  for (int it = 0; it < 8; ++it) {
    int p = it * 16384 + gw;              // pair index 0..131071
    int i = p >> 8, jp = p & 255;
    int j = jp * 2 + half;                // k-col
    int rr = i * 512 + j;                 // flat z row
    const float4 a = *(const float4*)(z + (size_t)rr * 128 + li * 4);
    float mb = (z_mask[rr] > 0.0f) ? 0.0f : -1e9f;

    float ss = a.x * a.x + a.y * a.y + a.z * a.z + a.w * a.w;
#pragma unroll
    for (int mk = 1; mk < 32; mk <<= 1) ss += __shfl_xor(ss, mk, 64);
    float rms = rsqrtf(ss * (1.0f / 128.0f) + 1e-5f);

    float y0 = a.x * wn.x, y1 = a.y * wn.y, y2 = a.z * wn.z, y3 = a.w * wn.w;
    f32x4 pl = y0 * wzl[0] + y1 * wzl[1] + y2 * wzl[2] + y3 * wzl[3];
    f32x4 ph = y0 * wzh[0] + y1 * wzh[1] + y2 * wzh[2] + y3 * wzh[3];

    int b0 = li & 1, b1 = (li >> 1) & 1, b2 = (li >> 2) & 1;
    float A[4] = {pl[0], pl[2], ph[0], ph[2]};
    float Bv[4] = {pl[1], pl[3], ph[1], ph[3]};
    float keep[4];
#pragma unroll
    for (int i2 = 0; i2 < 4; ++i2) {
      float send = b0 ? A[i2] : Bv[i2];
      float recv = __shfl_xor(send, 1, 64);
      keep[i2] = (b0 ? Bv[i2] : A[i2]) + recv;
    }
    float s2x = b1 ? keep[0] : keep[1];
    float s2y = b1 ? keep[2] : keep[3];
    float r2x = __shfl_xor(s2x, 2, 64);
    float r2y = __shfl_xor(s2y, 2, 64);
    float k2x = (b1 ? keep[1] : keep[0]) + r2x;
    float k2y = (b1 ? keep[3] : keep[2]) + r2y;
    float s3 = b2 ? k2x : k2y;
    float r3 = __shfl_xor(s3, 4, 64);
    float fin = (b2 ? k2y : k2x) + r3;           // head (li&7) partial (8 lanes)
    fin += __shfl_xor(fin, 8, 64);
    fin += __shfl_xor(fin, 16, 64);              // full 32-lane row sum

    float full = (fin * rms + mb) * LOG2E;
    float fo = __shfl_xor(full, 32, 64);         // partner (j0+1) value
    if (half == 0 && li < 8) {
      unsigned pk = cvt_pk_bf16(full, fo);       // (j0, j0+1)
      int j0 = jp * 2;
      int l = (i & 15) + 16 * ((j0 & 15) >> 2);
      size_t o = ((((size_t)li * 32 + (i >> 4)) * 32 + (j0 >> 4)) * 64 + l) * 2 +
                 ((jp) & 1);
      biasf[o] = pk;
    }
  }
}

// ---------------------------------------------------------------------------
// 128x128 MFMA GEMM mainloop (R8/R11-proven, 1-phase): global_load_lds
// width-16 staging into LINEAR LDS [128][32] with SOURCE-side XOR swizzle
// (chunk (row,q) holds global chunk (row, q ^ ((row>>1)&3))); reads apply
// the same XOR. REFUTED alternates: 2-phase dbuf (R12 +10us), K-in-LDS attn
// (R13 +24us), asymmetric block fusion (R14 +42us), f32 bias C-op (R15 +8us).
// ---------------------------------------------------------------------------
DI void gemm_mainloop_g(const unsigned short* a0, const unsigned short* a1,
                        const unsigned short* b0, const unsigned short* b1,
                        size_t Astep, unsigned short* At, unsigned short* Bts,
                        f32x4 acc[4][4]) {
  int tid = threadIdx.x, lane = tid & 63, w = tid >> 6;
  int wm = w >> 1, wn = w & 1;
  int r16 = lane & 15, g = lane >> 4;
  int gx = (g ^ ((r16 >> 1) & 3)) * 8;
  unsigned short* lA0 = At + w * 1024;
  unsigned short* lA1 = At + w * 1024 + 512;
  unsigned short* lB0 = Bts + w * 1024;
  unsigned short* lB1 = Bts + w * 1024 + 512;
  for (int ks = 0; ks < 8; ++ks) {
    gld16(a0 + ks * Astep, lA0);
    gld16(a1 + ks * Astep, lA1);
    gld16(b0 + ks * 32, lB0);
    gld16(b1 + ks * 32, lB1);
    __syncthreads();
    bf16x8 af[4], bfr[4];
#pragma unroll
    for (int i = 0; i < 4; ++i)
      af[i] = *(const bf16x8*)(At + (wm * 64 + i * 16 + r16) * 32 + gx);
#pragma unroll
    for (int j = 0; j < 4; ++j)
      bfr[j] = *(const bf16x8*)(Bts + (wn * 64 + j * 16 + r16) * 32 + gx);
#pragma unroll
    for (int i = 0; i < 4; ++i)
#pragma unroll
      for (int j = 0; j < 4; ++j)
        acc[i][j] = __builtin_amdgcn_mfma_f32_16x16x32_bf16(af[i], bfr[j],
                                                            acc[i][j], 0, 0, 0);
    __syncthreads();
  }
}

// GEMM 1: m_norm @ [Wq|Wk|Wv|Wg]. q pre-scaled by 1/sqrt(D)*log2(e).
__global__ __launch_bounds__(256) void k_gemm_qkvg(
    const unsigned short* __restrict__ m_norm, const unsigned short* __restrict__ Wt,
    const float* __restrict__ bg,
    unsigned short* __restrict__ q_ws, unsigned short* __restrict__ k_ws,
    unsigned short* __restrict__ v_ws, float* __restrict__ g_ws) {
  __shared__ unsigned short At[4096];
  __shared__ unsigned short Bts[4096];
  int mb = blockIdx.x * 128, nb = blockIdx.y * 128;
  int tid = threadIdx.x, lane = tid & 63, w = tid >> 6;
  int c0 = w * 128 + lane, c1 = c0 + 64;
  int row0 = c0 >> 2, q0 = (c0 & 3) ^ ((row0 >> 1) & 3);
  int row1 = c1 >> 2, q1 = (c1 & 3) ^ ((row1 >> 1) & 3);
  f32x4 acc[4][4] = {};
  gemm_mainloop_g(m_norm + (size_t)(mb + row0) * 256 + q0 * 8,
                  m_norm + (size_t)(mb + row1) * 256 + q1 * 8,
                  Wt + (size_t)(nb + row0) * 256 + q0 * 8,
                  Wt + (size_t)(nb + row1) * 256 + q1 * 8,
                  32, At, Bts, acc);
  int wm = w >> 1, wn = w & 1;
  int r16 = lane & 15, rg = lane >> 4;
#pragma unroll
  for (int i = 0; i < 4; ++i)
#pragma unroll
    for (int j = 0; j < 4; ++j) {
      int n = nb + wn * 64 + j * 16 + r16;
#pragma unroll
      for (int r = 0; r < 4; ++r) {
        int mrow = mb + wm * 64 + i * 16 + rg * 4 + r;
        int bb = mrow >> 9, s = mrow & 511;
        float v = acc[i][j][r];
        if (n < 768) {
          int tsel = n >> 8, hh = (n >> 5) & 7, dd = n & 31;
          unsigned short* dst = (tsel == 0) ? q_ws : (tsel == 1) ? k_ws : v_ws;
          float vv = (tsel == 0) ? v * QSCALE : v;
          dst[(((size_t)bb * 8 + hh) * 512 + s) * 32 + dd] = f2bf(vv);
        } else {
          int n2 = n & 255;
          g_ws[(size_t)mrow * 256 + n2] = v + bg[n2];
        }
      }
    }
}

// GEMM 2: attn_out [b][h][s][32] (pi-packed cols) @ Wt_o (rows pi-permuted),
// epilogue (+bo)*g -> fp32 out. A gathered per-head: K-step advances h.
__global__ __launch_bounds__(256) void k_gemm_out(
    const unsigned short* __restrict__ attn, const unsigned short* __restrict__ Wt_o,
    const float* __restrict__ bo, const float* __restrict__ g_ws,
    float* __restrict__ out) {
  __shared__ unsigned short At[4096];
  __shared__ unsigned short Bts[4096];
  int mb = blockIdx.x * 128, nb = blockIdx.y * 128;
  int tid = threadIdx.x, lane = tid & 63, w = tid >> 6;
  int c0 = w * 128 + lane, c1 = c0 + 64;
  int row0 = c0 >> 2, q0 = (c0 & 3) ^ ((row0 >> 1) & 3);
  int row1 = c1 >> 2, q1 = (c1 & 3) ^ ((row1 >> 1) & 3);
  int mrow0 = mb + row0, mrow1 = mb + row1;
  f32x4 acc[4][4] = {};
  gemm_mainloop_g(
      attn + ((size_t)(mrow0 >> 9) * 8) * 16384 + (size_t)(mrow0 & 511) * 32 + q0 * 8,
      attn + ((size_t)(mrow1 >> 9) * 8) * 16384 + (size_t)(mrow1 & 511) * 32 + q1 * 8,
      Wt_o + (size_t)(nb + row0) * 256 + q0 * 8,
      Wt_o + (size_t)(nb + row1) * 256 + q1 * 8,
      16384, At, Bts, acc);
  int wm = w >> 1, wn = w & 1;
  int r16 = lane & 15, rg = lane >> 4;
#pragma unroll
  for (int i = 0; i < 4; ++i)
#pragma unroll
    for (int j = 0; j < 4; ++j) {
      int n = nb + wn * 64 + j * 16 + r16;
#pragma unroll
      for (int r = 0; r < 4; ++r) {
        int mrow = mb + wm * 64 + i * 16 + rg * 4 + r;
        out[(size_t)mrow * 256 + n] = (acc[i][j][r] + bo[n]) * g_ws[(size_t)mrow * 256 + n];
      }
    }
}

// ---------------------------------------------------------------------------
// Attention (R11/R16 body + T1 XCD swizzle): the 64 blocks sharing one
// (quarter,h) bias slice (~256KB, re-read 64x) were consecutive bx -> HW
// round-robin spread them over 8 XCDs (each XCD refetches via L3). Remap
// wk = (bx&7)*256 + (bx>>3) (bijective: 2048%8==0): each XCD gets a
// contiguous 256-work chunk = 4 (quarter,h) groups -> its ~1MB of bias
// slices stays L2-resident. attn is latency-bound on exactly these loads.
// Body unchanged: swapped QK^T, P-in-regs, sigma-slot V, no max pass,
// setprio around MFMA pairs.
// ---------------------------------------------------------------------------
#define VT_LD 522
__global__ __launch_bounds__(256, 2) void k_attn(
    const unsigned short* __restrict__ q_ws, const unsigned short* __restrict__ k_ws,
    const unsigned short* __restrict__ v_ws, const unsigned* __restrict__ biasf,
    unsigned short* __restrict__ attn_out) {
  __shared__ unsigned short Vt[32 * VT_LD];        // 33,408 B
  int tid = threadIdx.x;
  int wave = tid >> 6, lane = tid & 63;
  int bx = blockIdx.x;
  int wk = ((bx & 7) << 8) + (bx >> 3);            // T1 XCD-contiguous work id
  int quarter = wk >> 9, h = (wk >> 6) & 7, b = wk & 63;
  size_t base = ((size_t)b * 8 + h) * (512 * 32);
  const unsigned short* qb = q_ws + base;
  const unsigned short* kb = k_ws + base;
  const unsigned short* vb = v_ws + base;
#pragma unroll
  for (int it = 0; it < 8; ++it) {
    int idx = it * 256 + tid;
    int s = idx >> 2, kk = idx & 3, d0 = kk * 8;
    bf16x8 vv = *(const bf16x8*)(vb + s * 32 + d0);
    int col = (s & ~31) + ((s >> 2) & 3) * 8 + ((s >> 4) & 1) * 4 + (s & 3);
#pragma unroll
    for (int j = 0; j < 8; ++j) Vt[(d0 + j) * VT_LD + col] = (unsigned short)vv[j];
  }
  __syncthreads();

  int r16 = lane & 15, g = lane >> 4;
  const unsigned* bh_ = biasf + (size_t)h * 131072 + lane * 2;
  unsigned short* ob = attn_out + base;            // [b][h][s][32]
  const f32x4 zero = {0.f, 0.f, 0.f, 0.f};

  for (int qt = 0; qt < 2; ++qt) {
    int qbase = quarter * 128 + (wave * 2 + qt) * 16;
    const unsigned* bq = bh_ + (size_t)(qbase >> 4) * 4096;
    bf16x8 qf = *(const bf16x8*)(qb + (qbase + r16) * 32 + g * 8);
    f32x4 o0 = zero, o1 = zero;
    float smA = 0.f, smB = 0.f, smC = 0.f, smD = 0.f;
#pragma unroll
    for (int c = 0; c < 16; ++c) {
      bf16x8 kf0 = *(const bf16x8*)(kb + ((c * 2) * 16 + r16) * 32 + g * 8);
      bf16x8 kf1 = *(const bf16x8*)(kb + ((c * 2 + 1) * 16 + r16) * 32 + g * 8);
      uint2 u0 = *(const uint2*)(bq + (c * 2) * 128);
      uint2 u1 = *(const uint2*)(bq + (c * 2 + 1) * 128);
      __builtin_amdgcn_s_setprio(1);
      f32x4 s0 = __builtin_amdgcn_mfma_f32_16x16x32_bf16(kf0, qf, zero, 0, 0, 0);
      f32x4 s1 = __builtin_amdgcn_mfma_f32_16x16x32_bf16(kf1, qf, zero, 0, 0, 0);
      __builtin_amdgcn_s_setprio(0);
      s0[0] += bflo(u0.x); s0[1] += bfhi(u0.x);
      s0[2] += bflo(u0.y); s0[3] += bfhi(u0.y);
      s1[0] += bflo(u1.x); s1[1] += bfhi(u1.x);
      s1[2] += bflo(u1.y); s1[3] += bfhi(u1.y);
#pragma unroll
      for (int r = 0; r < 4; ++r) {
        s0[r] = exp2f(s0[r]);
        s1[r] = exp2f(s1[r]);
      }
      smA += s0[0] + s1[0];
      smB += s0[1] + s1[1];
      smC += s0[2] + s1[2];
      smD += s0[3] + s1[3];
      union { unsigned u[4]; bf16x8 v; } pa;
      pa.u[0] = cvt_pk_bf16(s0[0], s0[1]);
      pa.u[1] = cvt_pk_bf16(s0[2], s0[3]);
      pa.u[2] = cvt_pk_bf16(s1[0], s1[1]);
      pa.u[3] = cvt_pk_bf16(s1[2], s1[3]);
      bf16x8 vf0 = *(const bf16x8*)(Vt + r16 * VT_LD + c * 32 + g * 8);
      bf16x8 vf1 = *(const bf16x8*)(Vt + (r16 + 16) * VT_LD + c * 32 + g * 8);
      __builtin_amdgcn_s_setprio(1);
      o0 = __builtin_amdgcn_mfma_f32_16x16x32_bf16(pa.v, vf0, o0, 0, 0, 0);
      o1 = __builtin_amdgcn_mfma_f32_16x16x32_bf16(pa.v, vf1, o1, 0, 0, 0);
      __builtin_amdgcn_s_setprio(0);
    }
    float S = smA + smB + smC + smD;
    S += __shfl_xor(S, 16, 64);
    S += __shfl_xor(S, 32, 64);
    float invS = 1.0f / S;
#pragma unroll
    for (int r = 0; r < 4; ++r) {
      float ir = __int_as_float(
          __builtin_amdgcn_ds_bpermute((4 * g + r) * 4, __float_as_int(invS)));
      int s = qbase + g * 4 + r;
      unsigned pk = cvt_pk_bf16(o0[r] * ir, o1[r] * ir);
      *(unsigned*)(ob + (size_t)s * 32 + r16 * 2) = pk;   // 64B runs
    }
  }
}

// ---------------------------------------------------------------------------
extern "C" void kernel_launch(void* const* d_in, const int* in_sizes, int n_in,
                              void* d_out, int out_size, void* d_ws, size_t ws_size,
                              hipStream_t stream) {
  (void)in_sizes; (void)n_in; (void)out_size; (void)ws_size;
  const float* m        = (const float*)d_in[0];
  const float* z        = (const float*)d_in[1];
  const float* z_mask   = (const float*)d_in[2];
  const float* w_norm_m = (const float*)d_in[3];
  const float* w_norm_z = (const float*)d_in[4];
  const float* Wq = (const float*)d_in[5];
  const float* Wk = (const float*)d_in[6];
  const float* Wv = (const float*)d_in[7];
  const float* Wz = (const float*)d_in[8];
  const float* Wg = (const float*)d_in[9];
  const float* bg = (const float*)d_in[10];
  const float* Wo = (const float*)d_in[11];
  const float* bo = (const float*)d_in[12];
  float* out = (float*)d_out;

  char* ws = (char*)d_ws;
  size_t off = 0;
  unsigned short* m_norm  = (unsigned short*)(ws + off); off += (size_t)32768 * 256 * 2;
  unsigned short* Wt_qkvg = (unsigned short*)(ws + off); off += (size_t)1024 * 256 * 2;
  unsigned short* Wt_o    = (unsigned short*)(ws + off); off += (size_t)256 * 256 * 2;
  unsigned short* q_ws    = (unsigned short*)(ws + off); off += (size_t)64 * 8 * 512 * 32 * 2;
  unsigned short* k_ws    = (unsigned short*)(ws + off); off += (size_t)64 * 8 * 512 * 32 * 2;
  unsigned short* v_ws    = (unsigned short*)(ws + off); off += (size_t)64 * 8 * 512 * 32 * 2;
  float* g_ws             = (float*)(ws + off);          off += (size_t)32768 * 256 * 4;
  unsigned* biasf         = (unsigned*)(ws + off);       off += (size_t)8 * 32 * 32 * 128 * 4;
  unsigned short* attn_out = m_norm;  // m_norm dead after k_gemm_qkvg

  hipLaunchKernelGGL(k_prep, dim3(9472), dim3(256), 0, stream,
                     Wq, Wk, Wv, Wg, Wo, Wt_qkvg, Wt_o, m, w_norm_m, m_norm);
  hipLaunchKernelGGL(k_pair_bias, dim3(4096), dim3(256), 0, stream,
                     z, z_mask, w_norm_z, Wz, biasf);
  hipLaunchKernelGGL(k_gemm_qkvg, dim3(256, 8), dim3(256), 0, stream,
                     m_norm, Wt_qkvg, bg, q_ws, k_ws, v_ws, g_ws);
  hipLaunchKernelGGL(k_attn, dim3(2048), dim3(256), 0, stream,
                     q_ws, k_ws, v_ws, biasf, attn_out);
  hipLaunchKernelGGL(k_gemm_out, dim3(256, 2), dim3(256), 0, stream,
                     attn_out, Wt_o, bo, g_ws, out);
}

// Round 18
// 176.798 us; speedup vs baseline: 1.0264x; 1.0264x over previous
//
#include <hip/hip_runtime.h>

typedef short bf16x8 __attribute__((ext_vector_type(8)));
typedef float f32x4 __attribute__((ext_vector_type(4)));

#define DI __device__ __forceinline__

#define LOG2E 1.44269504088896f
#define QSCALE (0.17677669529663687f * 1.44269504088896f)

static DI unsigned short f2bf(float f) {
  union { float f; unsigned u; } v; v.f = f;
  unsigned r = v.u + 0x7FFFu + ((v.u >> 16) & 1u);  // RNE
  return (unsigned short)(r >> 16);
}

static DI unsigned cvt_pk_bf16(float lo, float hi) {
  unsigned r;
  asm("v_cvt_pk_bf16_f32 %0, %1, %2" : "=v"(r) : "v"(lo), "v"(hi));
  return r;
}

static DI float bflo(unsigned u) { return __uint_as_float(u << 16); }
static DI float bfhi(unsigned u) { return __uint_as_float(u & 0xffff0000u); }

// Async global->LDS, 16B per lane. LDS dest is wave-uniform base + lane*16.
static DI void gld16(const void* g, void* l) {
  __builtin_amdgcn_global_load_lds((__attribute__((address_space(1))) void*)g,
                                   (__attribute__((address_space(3))) void*)l,
                                   16, 0, 0);
}

// ---------------------------------------------------------------------------
// PREP kernel: cast_weights (blocks 0..1279) + rmsnorm_m (blocks 1280..9471).
// Resource-symmetric fusion (both <=32 VGPR, no LDS, memory-bound).
// Wt_qkvg: [N=1024][K=256] bf16 n-major. Wt_o: rows k-PERMUTED with
// pi(h*32+d) = h*32 + (d&15)*2 + (d>>4) (k-perm on both operands = no-op).
// ---------------------------------------------------------------------------
__global__ __launch_bounds__(256) void k_prep(
    const float* __restrict__ Wq, const float* __restrict__ Wk,
    const float* __restrict__ Wv, const float* __restrict__ Wg,
    const float* __restrict__ Wo,
    unsigned short* __restrict__ Wt_qkvg, unsigned short* __restrict__ Wt_o,
    const float* __restrict__ m, const float* __restrict__ w_norm_m,
    unsigned short* __restrict__ m_norm) {
  int bx = blockIdx.x;
  if (bx < 1280) {
    int t = bx * 256 + threadIdx.x;
    if (t < 262144) {
      int n = t & 1023, kk = t >> 10;
      const float* W = (n < 256) ? Wq : (n < 512) ? Wk : (n < 768) ? Wv : Wg;
      Wt_qkvg[(size_t)n * 256 + kk] = f2bf(W[kk * 256 + (n & 255)]);
    } else if (t < 262144 + 65536) {
      int u = t - 262144;
      int n = u & 255, kk = u >> 8;
      int h = kk >> 5, e = kk & 31;
      int d = (e >> 1) + ((e & 1) << 4);  // pi^-1
      Wt_o[n * 256 + kk] = f2bf(Wo[(h * 32 + d) * 256 + n]);
    }
    return;
  }
  // rmsnorm: one wave per 256-elem row, float4 per lane
  int wave = threadIdx.x >> 6, lane = threadIdx.x & 63;
  int row = (bx - 1280) * 4 + wave;
  const float4 x = *(const float4*)(m + (size_t)row * 256 + lane * 4);
  float ss = x.x * x.x + x.y * x.y + x.z * x.z + x.w * x.w;
#pragma unroll
  for (int mk = 1; mk < 64; mk <<= 1) ss += __shfl_xor(ss, mk, 64);
  float rms = rsqrtf(ss * (1.0f / 256.0f) + 1e-5f);
  const float4 wv = *(const float4*)(w_norm_m + lane * 4);
  ushort4 o;
  o.x = f2bf(x.x * rms * wv.x);
  o.y = f2bf(x.y * rms * wv.y);
  o.z = f2bf(x.z * rms * wv.z);
  o.w = f2bf(x.w * rms * wv.w);
  *(ushort4*)(m_norm + (size_t)row * 256 + lane * 4) = o;
}

// ---------------------------------------------------------------------------
// Pair bias -> bf16 packed SWAPPED-C-fragment layout, pre-scaled by log2(e).
// Attn computes D[k][q] = mfma(K,Q): lane l needs bias(i=q=l&15 of its tile,
// k = t*16 + 4*(l>>4) + r). Pack pairs along k (j0 even, j0+1):
//   u32 biasf[h][i16][t][l][w], l = (i&15) + 16*((j0&15)>>2), w = (j0>>1)&1
// Wave: half 0 -> j0 (even), half 1 -> j0+1, same i; pack via shfl_xor(32).
// z loads coalesced (2 adjacent rows = 1KB per wave).
// ---------------------------------------------------------------------------
__global__ __launch_bounds__(256) void k_pair_bias(
    const float* __restrict__ z, const float* __restrict__ z_mask,
    const float* __restrict__ w_norm_z, const float* __restrict__ Wz,
    unsigned* __restrict__ biasf) {
  int gw = blockIdx.x * 4 + (threadIdx.x >> 6);   // global wave 0..16383
  int lane = threadIdx.x & 63;
  int half = lane >> 5, li = lane & 31;
  f32x4 wzl[4], wzh[4];
#pragma unroll
  for (int i = 0; i < 4; ++i) {
    wzl[i] = *(const f32x4*)(Wz + (li * 4 + i) * 8);
    wzh[i] = *(const f32x4*)(Wz + (li * 4 + i) * 8 + 4);
  }
  const float4 wn = *(const float4*)(w_norm_z + li * 4);

  for (int it = 0; it < 8; ++it) {
    int p = it * 16384 + gw;              // pair index 0..131071
    int i = p >> 8, jp = p & 255;
    int j = jp * 2 + half;                // k-col
    int rr = i * 512 + j;                 // flat z row
    const float4 a = *(const float4*)(z + (size_t)rr * 128 + li * 4);
    float mb = (z_mask[rr] > 0.0f) ? 0.0f : -1e9f;

    float ss = a.x * a.x + a.y * a.y + a.z * a.z + a.w * a.w;
#pragma unroll
    for (int mk = 1; mk < 32; mk <<= 1) ss += __shfl_xor(ss, mk, 64);
    float rms = rsqrtf(ss * (1.0f / 128.0f) + 1e-5f);

    float y0 = a.x * wn.x, y1 = a.y * wn.y, y2 = a.z * wn.z, y3 = a.w * wn.w;
    f32x4 pl = y0 * wzl[0] + y1 * wzl[1] + y2 * wzl[2] + y3 * wzl[3];
    f32x4 ph = y0 * wzh[0] + y1 * wzh[1] + y2 * wzh[2] + y3 * wzh[3];

    int b0 = li & 1, b1 = (li >> 1) & 1, b2 = (li >> 2) & 1;
    float A[4] = {pl[0], pl[2], ph[0], ph[2]};
    float Bv[4] = {pl[1], pl[3], ph[1], ph[3]};
    float keep[4];
#pragma unroll
    for (int i2 = 0; i2 < 4; ++i2) {
      float send = b0 ? A[i2] : Bv[i2];
      float recv = __shfl_xor(send, 1, 64);
      keep[i2] = (b0 ? Bv[i2] : A[i2]) + recv;
    }
    float s2x = b1 ? keep[0] : keep[1];
    float s2y = b1 ? keep[2] : keep[3];
    float r2x = __shfl_xor(s2x, 2, 64);
    float r2y = __shfl_xor(s2y, 2, 64);
    float k2x = (b1 ? keep[1] : keep[0]) + r2x;
    float k2y = (b1 ? keep[3] : keep[2]) + r2y;
    float s3 = b2 ? k2x : k2y;
    float r3 = __shfl_xor(s3, 4, 64);
    float fin = (b2 ? k2y : k2x) + r3;           // head (li&7) partial (8 lanes)
    fin += __shfl_xor(fin, 8, 64);
    fin += __shfl_xor(fin, 16, 64);              // full 32-lane row sum

    float full = (fin * rms + mb) * LOG2E;
    float fo = __shfl_xor(full, 32, 64);         // partner (j0+1) value
    if (half == 0 && li < 8) {
      unsigned pk = cvt_pk_bf16(full, fo);       // (j0, j0+1)
      int j0 = jp * 2;
      int l = (i & 15) + 16 * ((j0 & 15) >> 2);
      size_t o = ((((size_t)li * 32 + (i >> 4)) * 32 + (j0 >> 4)) * 64 + l) * 2 +
                 ((jp) & 1);
      biasf[o] = pk;
    }
  }
}

// ---------------------------------------------------------------------------
// 128x128 MFMA GEMM mainloop (R8/R11-proven, 1-phase): global_load_lds
// width-16 staging into LINEAR LDS [128][32] with SOURCE-side XOR swizzle
// (chunk (row,q) holds global chunk (row, q ^ ((row>>1)&3))); reads apply
// the same XOR. REFUTED alternates: 2-phase dbuf (R12 +10us), K-in-LDS attn
// (R13 +24us), asym block fusion (R14 +42us), f32 bias C-op (R15 +8us),
// attn XCD swizzle (R17 +1.7us).
// ---------------------------------------------------------------------------
DI void gemm_mainloop_g(const unsigned short* a0, const unsigned short* a1,
                        const unsigned short* b0, const unsigned short* b1,
                        size_t Astep, unsigned short* At, unsigned short* Bts,
                        f32x4 acc[4][4]) {
  int tid = threadIdx.x, lane = tid & 63, w = tid >> 6;
  int wm = w >> 1, wn = w & 1;
  int r16 = lane & 15, g = lane >> 4;
  int gx = (g ^ ((r16 >> 1) & 3)) * 8;
  unsigned short* lA0 = At + w * 1024;
  unsigned short* lA1 = At + w * 1024 + 512;
  unsigned short* lB0 = Bts + w * 1024;
  unsigned short* lB1 = Bts + w * 1024 + 512;
  for (int ks = 0; ks < 8; ++ks) {
    gld16(a0 + ks * Astep, lA0);
    gld16(a1 + ks * Astep, lA1);
    gld16(b0 + ks * 32, lB0);
    gld16(b1 + ks * 32, lB1);
    __syncthreads();
    bf16x8 af[4], bfr[4];
#pragma unroll
    for (int i = 0; i < 4; ++i)
      af[i] = *(const bf16x8*)(At + (wm * 64 + i * 16 + r16) * 32 + gx);
#pragma unroll
    for (int j = 0; j < 4; ++j)
      bfr[j] = *(const bf16x8*)(Bts + (wn * 64 + j * 16 + r16) * 32 + gx);
#pragma unroll
    for (int i = 0; i < 4; ++i)
#pragma unroll
      for (int j = 0; j < 4; ++j)
        acc[i][j] = __builtin_amdgcn_mfma_f32_16x16x32_bf16(af[i], bfr[j],
                                                            acc[i][j], 0, 0, 0);
    __syncthreads();
  }
}

// GEMM 1: m_norm @ [Wq|Wk|Wv|Wg]. q pre-scaled by 1/sqrt(D)*log2(e).
__global__ __launch_bounds__(256) void k_gemm_qkvg(
    const unsigned short* __restrict__ m_norm, const unsigned short* __restrict__ Wt,
    const float* __restrict__ bg,
    unsigned short* __restrict__ q_ws, unsigned short* __restrict__ k_ws,
    unsigned short* __restrict__ v_ws, float* __restrict__ g_ws) {
  __shared__ unsigned short At[4096];
  __shared__ unsigned short Bts[4096];
  int mb = blockIdx.x * 128, nb = blockIdx.y * 128;
  int tid = threadIdx.x, lane = tid & 63, w = tid >> 6;
  int c0 = w * 128 + lane, c1 = c0 + 64;
  int row0 = c0 >> 2, q0 = (c0 & 3) ^ ((row0 >> 1) & 3);
  int row1 = c1 >> 2, q1 = (c1 & 3) ^ ((row1 >> 1) & 3);
  f32x4 acc[4][4] = {};
  gemm_mainloop_g(m_norm + (size_t)(mb + row0) * 256 + q0 * 8,
                  m_norm + (size_t)(mb + row1) * 256 + q1 * 8,
                  Wt + (size_t)(nb + row0) * 256 + q0 * 8,
                  Wt + (size_t)(nb + row1) * 256 + q1 * 8,
                  32, At, Bts, acc);
  int wm = w >> 1, wn = w & 1;
  int r16 = lane & 15, rg = lane >> 4;
#pragma unroll
  for (int i = 0; i < 4; ++i)
#pragma unroll
    for (int j = 0; j < 4; ++j) {
      int n = nb + wn * 64 + j * 16 + r16;
#pragma unroll
      for (int r = 0; r < 4; ++r) {
        int mrow = mb + wm * 64 + i * 16 + rg * 4 + r;
        int bb = mrow >> 9, s = mrow & 511;
        float v = acc[i][j][r];
        if (n < 768) {
          int tsel = n >> 8, hh = (n >> 5) & 7, dd = n & 31;
          unsigned short* dst = (tsel == 0) ? q_ws : (tsel == 1) ? k_ws : v_ws;
          float vv = (tsel == 0) ? v * QSCALE : v;
          dst[(((size_t)bb * 8 + hh) * 512 + s) * 32 + dd] = f2bf(vv);
        } else {
          int n2 = n & 255;
          g_ws[(size_t)mrow * 256 + n2] = v + bg[n2];
        }
      }
    }
}

// GEMM 2: attn_out [b][h][s][32] (pi-packed cols) @ Wt_o (rows pi-permuted),
// epilogue (+bo)*g -> fp32 out. A gathered per-head: K-step advances h.
__global__ __launch_bounds__(256) void k_gemm_out(
    const unsigned short* __restrict__ attn, const unsigned short* __restrict__ Wt_o,
    const float* __restrict__ bo, const float* __restrict__ g_ws,
    float* __restrict__ out) {
  __shared__ unsigned short At[4096];
  __shared__ unsigned short Bts[4096];
  int mb = blockIdx.x * 128, nb = blockIdx.y * 128;
  int tid = threadIdx.x, lane = tid & 63, w = tid >> 6;
  int c0 = w * 128 + lane, c1 = c0 + 64;
  int row0 = c0 >> 2, q0 = (c0 & 3) ^ ((row0 >> 1) & 3);
  int row1 = c1 >> 2, q1 = (c1 & 3) ^ ((row1 >> 1) & 3);
  int mrow0 = mb + row0, mrow1 = mb + row1;
  f32x4 acc[4][4] = {};
  gemm_mainloop_g(
      attn + ((size_t)(mrow0 >> 9) * 8) * 16384 + (size_t)(mrow0 & 511) * 32 + q0 * 8,
      attn + ((size_t)(mrow1 >> 9) * 8) * 16384 + (size_t)(mrow1 & 511) * 32 + q1 * 8,
      Wt_o + (size_t)(nb + row0) * 256 + q0 * 8,
      Wt_o + (size_t)(nb + row1) * 256 + q1 * 8,
      16384, At, Bts, acc);
  int wm = w >> 1, wn = w & 1;
  int r16 = lane & 15, rg = lane >> 4;
#pragma unroll
  for (int i = 0; i < 4; ++i)
#pragma unroll
    for (int j = 0; j < 4; ++j) {
      int n = nb + wn * 64 + j * 16 + r16;
#pragma unroll
      for (int r = 0; r < 4; ++r) {
        int mrow = mb + wm * 64 + i * 16 + rg * 4 + r;
        out[(size_t)mrow * 256 + n] = (acc[i][j][r] + bo[n]) * g_ws[(size_t)mrow * 256 + n];
      }
    }
}

// ---------------------------------------------------------------------------
// Attention (R11-proven final): swapped QK^T (mfma(K,Q) -> D[k][q],
// q = lane&15) so P is a valid PV A-operand IN REGISTERS. Bias added
// post-MFMA from packed bf16 fragments (uint2/lane/t). PV k-order sigma:
// group g holds k in {4g..4g+3, 16+4g..16+4g+3}; V staged at slot
// 8*((sc>>2)&3)+4*((sc>>4)&1)+(sc&3) so vf = one ds_read_b128. VT_LD=522.
// No max pass (scores bounded; mask -1.4e9 -> exp2 = 0); 1/sum at output.
// setprio around MFMA pairs (T5, barrier-free independent waves).
// Grid 2048 = quarter*512 + h*64 + b. (R17 XCD swizzle: null, reverted.)
// ---------------------------------------------------------------------------
#define VT_LD 522
__global__ __launch_bounds__(256, 2) void k_attn(
    const unsigned short* __restrict__ q_ws, const unsigned short* __restrict__ k_ws,
    const unsigned short* __restrict__ v_ws, const unsigned* __restrict__ biasf,
    unsigned short* __restrict__ attn_out) {
  __shared__ unsigned short Vt[32 * VT_LD];        // 33,408 B
  int tid = threadIdx.x;
  int wave = tid >> 6, lane = tid & 63;
  int bx = blockIdx.x;
  int quarter = bx >> 9, h = (bx >> 6) & 7, b = bx & 63;
  size_t base = ((size_t)b * 8 + h) * (512 * 32);
  const unsigned short* qb = q_ws + base;
  const unsigned short* kb = k_ws + base;
  const unsigned short* vb = v_ws + base;
#pragma unroll
  for (int it = 0; it < 8; ++it) {
    int idx = it * 256 + tid;
    int s = idx >> 2, kk = idx & 3, d0 = kk * 8;
    bf16x8 vv = *(const bf16x8*)(vb + s * 32 + d0);
    int col = (s & ~31) + ((s >> 2) & 3) * 8 + ((s >> 4) & 1) * 4 + (s & 3);
#pragma unroll
    for (int j = 0; j < 8; ++j) Vt[(d0 + j) * VT_LD + col] = (unsigned short)vv[j];
  }
  __syncthreads();

  int r16 = lane & 15, g = lane >> 4;
  const unsigned* bh_ = biasf + (size_t)h * 131072 + lane * 2;
  unsigned short* ob = attn_out + base;            // [b][h][s][32]
  const f32x4 zero = {0.f, 0.f, 0.f, 0.f};

  for (int qt = 0; qt < 2; ++qt) {
    int qbase = quarter * 128 + (wave * 2 + qt) * 16;
    const unsigned* bq = bh_ + (size_t)(qbase >> 4) * 4096;
    bf16x8 qf = *(const bf16x8*)(qb + (qbase + r16) * 32 + g * 8);
    f32x4 o0 = zero, o1 = zero;
    float smA = 0.f, smB = 0.f, smC = 0.f, smD = 0.f;
#pragma unroll
    for (int c = 0; c < 16; ++c) {
      bf16x8 kf0 = *(const bf16x8*)(kb + ((c * 2) * 16 + r16) * 32 + g * 8);
      bf16x8 kf1 = *(const bf16x8*)(kb + ((c * 2 + 1) * 16 + r16) * 32 + g * 8);
      uint2 u0 = *(const uint2*)(bq + (c * 2) * 128);
      uint2 u1 = *(const uint2*)(bq + (c * 2 + 1) * 128);
      __builtin_amdgcn_s_setprio(1);
      f32x4 s0 = __builtin_amdgcn_mfma_f32_16x16x32_bf16(kf0, qf, zero, 0, 0, 0);
      f32x4 s1 = __builtin_amdgcn_mfma_f32_16x16x32_bf16(kf1, qf, zero, 0, 0, 0);
      __builtin_amdgcn_s_setprio(0);
      s0[0] += bflo(u0.x); s0[1] += bfhi(u0.x);
      s0[2] += bflo(u0.y); s0[3] += bfhi(u0.y);
      s1[0] += bflo(u1.x); s1[1] += bfhi(u1.x);
      s1[2] += bflo(u1.y); s1[3] += bfhi(u1.y);
#pragma unroll
      for (int r = 0; r < 4; ++r) {
        s0[r] = exp2f(s0[r]);
        s1[r] = exp2f(s1[r]);
      }
      smA += s0[0] + s1[0];
      smB += s0[1] + s1[1];
      smC += s0[2] + s1[2];
      smD += s0[3] + s1[3];
      union { unsigned u[4]; bf16x8 v; } pa;
      pa.u[0] = cvt_pk_bf16(s0[0], s0[1]);
      pa.u[1] = cvt_pk_bf16(s0[2], s0[3]);
      pa.u[2] = cvt_pk_bf16(s1[0], s1[1]);
      pa.u[3] = cvt_pk_bf16(s1[2], s1[3]);
      bf16x8 vf0 = *(const bf16x8*)(Vt + r16 * VT_LD + c * 32 + g * 8);
      bf16x8 vf1 = *(const bf16x8*)(Vt + (r16 + 16) * VT_LD + c * 32 + g * 8);
      __builtin_amdgcn_s_setprio(1);
      o0 = __builtin_amdgcn_mfma_f32_16x16x32_bf16(pa.v, vf0, o0, 0, 0, 0);
      o1 = __builtin_amdgcn_mfma_f32_16x16x32_bf16(pa.v, vf1, o1, 0, 0, 0);
      __builtin_amdgcn_s_setprio(0);
    }
    float S = smA + smB + smC + smD;
    S += __shfl_xor(S, 16, 64);
    S += __shfl_xor(S, 32, 64);
    float invS = 1.0f / S;
#pragma unroll
    for (int r = 0; r < 4; ++r) {
      float ir = __int_as_float(
          __builtin_amdgcn_ds_bpermute((4 * g + r) * 4, __float_as_int(invS)));
      int s = qbase + g * 4 + r;
      unsigned pk = cvt_pk_bf16(o0[r] * ir, o1[r] * ir);
      *(unsigned*)(ob + (size_t)s * 32 + r16 * 2) = pk;   // 64B runs
    }
  }
}

// ---------------------------------------------------------------------------
extern "C" void kernel_launch(void* const* d_in, const int* in_sizes, int n_in,
                              void* d_out, int out_size, void* d_ws, size_t ws_size,
                              hipStream_t stream) {
  (void)in_sizes; (void)n_in; (void)out_size; (void)ws_size;
  const float* m        = (const float*)d_in[0];
  const float* z        = (const float*)d_in[1];
  const float* z_mask   = (const float*)d_in[2];
  const float* w_norm_m = (const float*)d_in[3];
  const float* w_norm_z = (const float*)d_in[4];
  const float* Wq = (const float*)d_in[5];
  const float* Wk = (const float*)d_in[6];
  const float* Wv = (const float*)d_in[7];
  const float* Wz = (const float*)d_in[8];
  const float* Wg = (const float*)d_in[9];
  const float* bg = (const float*)d_in[10];
  const float* Wo = (const float*)d_in[11];
  const float* bo = (const float*)d_in[12];
  float* out = (float*)d_out;

  char* ws = (char*)d_ws;
  size_t off = 0;
  unsigned short* m_norm  = (unsigned short*)(ws + off); off += (size_t)32768 * 256 * 2;
  unsigned short* Wt_qkvg = (unsigned short*)(ws + off); off += (size_t)1024 * 256 * 2;
  unsigned short* Wt_o    = (unsigned short*)(ws + off); off += (size_t)256 * 256 * 2;
  unsigned short* q_ws    = (unsigned short*)(ws + off); off += (size_t)64 * 8 * 512 * 32 * 2;
  unsigned short* k_ws    = (unsigned short*)(ws + off); off += (size_t)64 * 8 * 512 * 32 * 2;
  unsigned short* v_ws    = (unsigned short*)(ws + off); off += (size_t)64 * 8 * 512 * 32 * 2;
  float* g_ws             = (float*)(ws + off);          off += (size_t)32768 * 256 * 4;
  unsigned* biasf         = (unsigned*)(ws + off);       off += (size_t)8 * 32 * 32 * 128 * 4;
  unsigned short* attn_out = m_norm;  // m_norm dead after k_gemm_qkvg

  hipLaunchKernelGGL(k_prep, dim3(9472), dim3(256), 0, stream,
                     Wq, Wk, Wv, Wg, Wo, Wt_qkvg, Wt_o, m, w_norm_m, m_norm);
  hipLaunchKernelGGL(k_pair_bias, dim3(4096), dim3(256), 0, stream,
                     z, z_mask, w_norm_z, Wz, biasf);
  hipLaunchKernelGGL(k_gemm_qkvg, dim3(256, 8), dim3(256), 0, stream,
                     m_norm, Wt_qkvg, bg, q_ws, k_ws, v_ws, g_ws);
  hipLaunchKernelGGL(k_attn, dim3(2048), dim3(256), 0, stream,
                     q_ws, k_ws, v_ws, biasf, attn_out);
  hipLaunchKernelGGL(k_gemm_out, dim3(256, 2), dim3(256), 0, stream,
                     attn_out, Wt_o, bo, g_ws, out);
}